// Round 3
// baseline (1310.934 us; speedup 1.0000x reference)
//
#include <hip/hip_runtime.h>
#include <hip/hip_bf16.h>

#define N_NODES 100000
#define N_EDGES 1000000
#define NPAD    100352          // nodes padded to 98*1024 for the scan
#define NT      98              // scan tiles of 1024

__device__ __forceinline__ float bf_to_f(unsigned short u) {
    union { unsigned int i; float f; } c; c.i = ((unsigned int)u) << 16; return c.f;
}
__device__ __forceinline__ unsigned short f_to_bf(float f) {
    union { float f; unsigned int i; } c; c.f = f;
    unsigned int x = c.i;
    unsigned int r = x + 0x7fffu + ((x >> 16) & 1u);   // RTNE
    return (unsigned short)(r >> 16);
}
__device__ __forceinline__ int clampi(int x) {
    return x < 0 ? 0 : (x >= N_NODES ? N_NODES - 1 : x);
}

// K1: per-node score dots (f32). One wave per node; lane handles a float2.
__global__ __launch_bounds__(256)
void k_node_scores(const float* __restrict__ ent,
                   const float* __restrict__ attf,
                   const float* __restrict__ aw,     // 256 floats
                   float* __restrict__ s_ent, float* __restrict__ s_att) {
    int node = (int)((blockIdx.x * blockDim.x + threadIdx.x) >> 6);
    int lane = threadIdx.x & 63;
    if (node >= N_NODES) return;
    const float2* aw2 = (const float2*)aw;
    float2 we = aw2[lane];          // a_w[2*lane : 2*lane+2]
    float2 wa = aw2[64 + lane];     // a_w[128+2*lane : ...]
    float2 e2 = ((const float2*)ent)[(size_t)node * 64 + lane];
    float2 a2 = ((const float2*)attf)[(size_t)node * 64 + lane];
    float se = e2.x * we.x + e2.y * we.y;
    float sa = a2.x * wa.x + a2.y * wa.y;
#pragma unroll
    for (int off = 32; off >= 1; off >>= 1) {
        se += __shfl_xor(se, off, 64);
        sa += __shfl_xor(sa, off, 64);
    }
    if (lane == 0) { s_ent[node] = se; s_att[node] = sa; }
}

// K2: histogram of head nodes.
__global__ __launch_bounds__(256)
void k_hist(const int* __restrict__ tri, int* __restrict__ hist) {
    int e = (int)(blockIdx.x * blockDim.x + threadIdx.x);
    if (e >= N_EDGES) return;
    atomicAdd(&hist[clampi(tri[3 * e])], 1);
}

// K3a: per-tile exclusive scan (1024-wide tiles) + tile sums.
__global__ __launch_bounds__(1024)
void k_scan1(const int* __restrict__ hist, int* __restrict__ offs, int* __restrict__ bsums) {
    __shared__ int sd[1024];
    int t = threadIdx.x;
    int i = (int)blockIdx.x * 1024 + t;
    int x = hist[i];
    sd[t] = x;
    __syncthreads();
    for (int d = 1; d < 1024; d <<= 1) {
        int v = (t >= d) ? sd[t - d] : 0;
        __syncthreads();
        sd[t] += v;
        __syncthreads();
    }
    offs[i] = sd[t] - x;                 // exclusive
    if (t == 1023) bsums[blockIdx.x] = sd[t];
}

// K3b: scan the 98 tile sums.
__global__ void k_scan2(int* __restrict__ bsums) {
    if (threadIdx.x == 0 && blockIdx.x == 0) {
        int acc = 0;
        for (int i = 0; i < NT; ++i) { int v = bsums[i]; bsums[i] = acc; acc += v; }
    }
}

// K3c: add tile offsets.
__global__ __launch_bounds__(256)
void k_scan3(int* __restrict__ offs, const int* __restrict__ bsums) {
    int i = (int)(blockIdx.x * blockDim.x + threadIdx.x);
    if (i >= NPAD) return;
    offs[i] += bsums[i >> 10];
}

// K4: per-edge score + row_sum + bucket scatter (counting sort by h).
__global__ __launch_bounds__(256)
void k_edge_bucket(const int* __restrict__ tri,
                   const float* __restrict__ s_ent, const float* __restrict__ s_att,
                   const float* __restrict__ abp,
                   const int* __restrict__ offs, int* __restrict__ cursor,
                   float* __restrict__ row_sum,
                   int* __restrict__ sa, int* __restrict__ sv, float* __restrict__ ssc) {
    int e = (int)(blockIdx.x * blockDim.x + threadIdx.x);
    if (e >= N_EDGES) return;
    int h = clampi(tri[3 * e]);
    int a = clampi(tri[3 * e + 1]);
    int v = clampi(tri[3 * e + 2]);
    float s = s_ent[h] + s_att[a] + abp[0];
    s = s > 0.f ? s : 0.2f * s;          // leaky_relu(0.2)
    float sc = __expf(s);
    atomicAdd(&row_sum[h], sc);
    int pos = offs[h] + atomicAdd(&cursor[h], 1);
    sa[pos] = a; sv[pos] = v; ssc[pos] = sc;
}

// K5: per-node aggregation + fused GEMV(W) + elu + f32 store.
// 16 nodes per 256-thread block; W (192x128) staged bf16 in LDS (48 KB).
#define NODES_PER_BLK 16
__global__ __launch_bounds__(256)
void k_agg(const int* __restrict__ offs, const float* __restrict__ row_sum,
           const int* __restrict__ sa, const int* __restrict__ sv,
           const float* __restrict__ ssc,
           const float* __restrict__ attf, const float* __restrict__ valf,
           const float* __restrict__ W,
           const float* __restrict__ ent, float* __restrict__ out) {
    __shared__ unsigned short Wl[192 * 128];   // bf16 copy of W
    __shared__ float g[192];
    int t = threadIdx.x;
    for (int i = t; i < 192 * 128; i += 256) Wl[i] = f_to_bf(W[i]);
    int base = (int)blockIdx.x * NODES_PER_BLK;
    for (int nn = 0; nn < NODES_PER_BLK; ++nn) {
        int n = base + nn;
        if (t < 192) g[t] = 0.f;
        __syncthreads();                  // Wl ready (iter 0) + g zeroed
        int beg = offs[n], end = offs[n + 1];
        float rs = row_sum[n];
        rs = rs > 0.f ? rs : 1.f;
        if (t < 96) {
            for (int i = beg; i < end; ++i) {
                float p = ssc[i] / rs;
                if (t < 64) {
                    float2 f = ((const float2*)attf)[(size_t)sa[i] * 64 + t];
                    g[2 * t]     += p * f.x;
                    g[2 * t + 1] += p * f.y;
                } else {
                    int u = t - 64;
                    float2 f = ((const float2*)valf)[(size_t)sv[i] * 32 + u];
                    g[128 + 2 * u]     += p * f.x;
                    g[128 + 2 * u + 1] += p * f.y;
                }
            }
        }
        __syncthreads();
        if (t < 128) {
            float acc = 0.f;
#pragma unroll 8
            for (int k = 0; k < 192; ++k) acc += g[k] * bf_to_f(Wl[k * 128 + t]);
            float x = acc + ent[(size_t)n * 128 + t];
            float y = x > 0.f ? x : expm1f(x);
            out[(size_t)n * 128 + t] = y;
        }
        __syncthreads();                  // protect g before next node
    }
}

extern "C" void kernel_launch(void* const* d_in, const int* in_sizes, int n_in,
                              void* d_out, int out_size, void* d_ws, size_t ws_size,
                              hipStream_t stream) {
    const int*   tri  = (const int*)d_in[0];
    const float* ent  = (const float*)d_in[1];
    const float* attf = (const float*)d_in[2];
    const float* valf = (const float*)d_in[3];
    const float* aw   = (const float*)d_in[4];
    const float* ab   = (const float*)d_in[5];
    const float* W    = (const float*)d_in[6];
    float* out = (float*)d_out;

    char* ws = (char*)d_ws;
    size_t off = 0;
    // memset region: hist + cursor + row_sum (contiguous)
    int*   hist    = (int*)(ws + off);   off += NPAD * 4;
    int*   cursor  = (int*)(ws + off);   off += NPAD * 4;
    float* row_sum = (float*)(ws + off); off += NPAD * 4;
    size_t zero_len = off;
    int*   offs    = (int*)(ws + off);   off += NPAD * 4;
    int*   bsums   = (int*)(ws + off);   off += 512;
    float* s_ent   = (float*)(ws + off); off += NPAD * 4;
    float* s_att   = (float*)(ws + off); off += NPAD * 4;
    int*   sa      = (int*)(ws + off);   off += (size_t)N_EDGES * 4;
    int*   sv      = (int*)(ws + off);   off += (size_t)N_EDGES * 4;
    float* ssc     = (float*)(ws + off); off += (size_t)N_EDGES * 4;
    // total ~14.4 MB

    hipMemsetAsync(ws, 0, zero_len, stream);

    k_node_scores<<<N_NODES / 4, 256, 0, stream>>>(ent, attf, aw, s_ent, s_att);
    k_hist<<<(N_EDGES + 255) / 256, 256, 0, stream>>>(tri, hist);
    k_scan1<<<NT, 1024, 0, stream>>>(hist, offs, bsums);
    k_scan2<<<1, 64, 0, stream>>>(bsums);
    k_scan3<<<NPAD / 256, 256, 0, stream>>>(offs, bsums);
    k_edge_bucket<<<(N_EDGES + 255) / 256, 256, 0, stream>>>(tri, s_ent, s_att, ab, offs, cursor,
                                                             row_sum, sa, sv, ssc);
    k_agg<<<N_NODES / NODES_PER_BLK, 256, 0, stream>>>(offs, row_sum, sa, sv, ssc,
                                                       attf, valf, W, ent, out);
}

// Round 4
// 694.924 us; speedup vs baseline: 1.8864x; 1.8864x over previous
//
#include <hip/hip_runtime.h>
#include <hip/hip_bf16.h>

#define N_NODES 100000
#define N_EDGES 1000000
#define NPAD    100352          // nodes padded to 98*1024 for the scan
#define NT      98              // scan tiles of 1024

__device__ __forceinline__ float bf_to_f(unsigned short u) {
    union { unsigned int i; float f; } c; c.i = ((unsigned int)u) << 16; return c.f;
}
__device__ __forceinline__ unsigned short f_to_bf(float f) {
    union { float f; unsigned int i; } c; c.f = f;
    unsigned int x = c.i;
    unsigned int r = x + 0x7fffu + ((x >> 16) & 1u);   // RTNE
    return (unsigned short)(r >> 16);
}
__device__ __forceinline__ int clampi(int x) {
    return x < 0 ? 0 : (x >= N_NODES ? N_NODES - 1 : x);
}

// K1: per-node score dots (f32). One wave per node; lane handles a float2.
__global__ __launch_bounds__(256)
void k_node_scores(const float* __restrict__ ent,
                   const float* __restrict__ attf,
                   const float* __restrict__ aw,     // 256 floats
                   float* __restrict__ s_ent, float* __restrict__ s_att) {
    int node = (int)((blockIdx.x * blockDim.x + threadIdx.x) >> 6);
    int lane = threadIdx.x & 63;
    if (node >= N_NODES) return;
    const float2* aw2 = (const float2*)aw;
    float2 we = aw2[lane];
    float2 wa = aw2[64 + lane];
    float2 e2 = ((const float2*)ent)[(size_t)node * 64 + lane];
    float2 a2 = ((const float2*)attf)[(size_t)node * 64 + lane];
    float se = e2.x * we.x + e2.y * we.y;
    float sa = a2.x * wa.x + a2.y * wa.y;
#pragma unroll
    for (int off = 32; off >= 1; off >>= 1) {
        se += __shfl_xor(se, off, 64);
        sa += __shfl_xor(sa, off, 64);
    }
    if (lane == 0) { s_ent[node] = se; s_att[node] = sa; }
}

// K2: histogram of head nodes.
__global__ __launch_bounds__(256)
void k_hist(const int* __restrict__ tri, int* __restrict__ hist) {
    int e = (int)(blockIdx.x * blockDim.x + threadIdx.x);
    if (e >= N_EDGES) return;
    atomicAdd(&hist[clampi(tri[3 * e])], 1);
}

// K3a: per-tile exclusive scan (1024-wide tiles) + tile sums.
__global__ __launch_bounds__(1024)
void k_scan1(const int* __restrict__ hist, int* __restrict__ offs, int* __restrict__ bsums) {
    __shared__ int sd[1024];
    int t = threadIdx.x;
    int i = (int)blockIdx.x * 1024 + t;
    int x = hist[i];
    sd[t] = x;
    __syncthreads();
    for (int d = 1; d < 1024; d <<= 1) {
        int v = (t >= d) ? sd[t - d] : 0;
        __syncthreads();
        sd[t] += v;
        __syncthreads();
    }
    offs[i] = sd[t] - x;                 // exclusive
    if (t == 1023) bsums[blockIdx.x] = sd[t];
}

// K3b: scan the 98 tile sums.
__global__ void k_scan2(int* __restrict__ bsums) {
    if (threadIdx.x == 0 && blockIdx.x == 0) {
        int acc = 0;
        for (int i = 0; i < NT; ++i) { int v = bsums[i]; bsums[i] = acc; acc += v; }
    }
}

// K3c: add tile offsets.
__global__ __launch_bounds__(256)
void k_scan3(int* __restrict__ offs, const int* __restrict__ bsums) {
    int i = (int)(blockIdx.x * blockDim.x + threadIdx.x);
    if (i >= NPAD) return;
    offs[i] += bsums[i >> 10];
}

// K4: per-edge score + row_sum + bucket scatter (counting sort by h).
__global__ __launch_bounds__(256)
void k_edge_bucket(const int* __restrict__ tri,
                   const float* __restrict__ s_ent, const float* __restrict__ s_att,
                   const float* __restrict__ abp,
                   const int* __restrict__ offs, int* __restrict__ cursor,
                   float* __restrict__ row_sum,
                   int* __restrict__ sa, int* __restrict__ sv, float* __restrict__ ssc) {
    int e = (int)(blockIdx.x * blockDim.x + threadIdx.x);
    if (e >= N_EDGES) return;
    int h = clampi(tri[3 * e]);
    int a = clampi(tri[3 * e + 1]);
    int v = clampi(tri[3 * e + 2]);
    float s = s_ent[h] + s_att[a] + abp[0];
    s = s > 0.f ? s : 0.2f * s;          // leaky_relu(0.2)
    float sc = __expf(s);
    atomicAdd(&row_sum[h], sc);
    int pos = offs[h] + atomicAdd(&cursor[h], 1);
    sa[pos] = a; sv[pos] = v; ssc[pos] = sc;
}

// K5: wave-per-node aggregation + fused GEMV(W) + elu + f32 store.
// 4 waves/block, each wave does NPB/4 nodes; W staged once as packed bf16 pairs
// (Wl[k*64+jj] = cols 2jj,2jj+1 of row k). Register gather accumulation, no
// barriers after staging.
#define NPB 16
__global__ __launch_bounds__(256)
void k_agg(const int* __restrict__ offs, const float* __restrict__ row_sum,
           const int* __restrict__ sa, const int* __restrict__ sv,
           const float* __restrict__ ssc,
           const float* __restrict__ attf, const float* __restrict__ valf,
           const float* __restrict__ W,
           const float* __restrict__ ent, float* __restrict__ out) {
    __shared__ unsigned int Wl[192 * 64];   // 48 KB: packed bf16 col-pairs
    __shared__ float gbuf[4][192];          // per-wave g vector
    int t = threadIdx.x;
    for (int i = t; i < 192 * 64; i += 256) {
        float2 w2 = ((const float2*)W)[i];
        Wl[i] = ((unsigned int)f_to_bf(w2.y) << 16) | (unsigned int)f_to_bf(w2.x);
    }
    __syncthreads();                        // only block-wide barrier
    int w = t >> 6, lane = t & 63;
    float* g = gbuf[w];
    int base = (int)blockIdx.x * NPB + w;
    for (int it = 0; it < NPB / 4; ++it) {
        int n = base + it * 4;
        int beg = offs[n], end = offs[n + 1];
        float a0 = 0.f, a1 = 0.f, v0 = 0.f;
        for (int i = beg; i < end; ++i) {
            int a = sa[i], v = sv[i];
            float sc = ssc[i];
            float2 f = ((const float2*)attf)[(size_t)a * 64 + lane];
            float fv = valf[(size_t)v * 64 + lane];
            a0 += sc * f.x; a1 += sc * f.y; v0 += sc * fv;
        }
        float rs = row_sum[n];
        float inv = rs > 0.f ? 1.f / rs : 0.f;   // softmax denom factored out
        float2 gp; gp.x = a0 * inv; gp.y = a1 * inv;
        ((float2*)g)[lane] = gp;                 // g[2l],g[2l+1]
        g[128 + lane] = v0 * inv;
        // GEMV: lane computes output cols 2*lane, 2*lane+1
        float acc0 = 0.f, acc1 = 0.f;
#pragma unroll 4
        for (int k4 = 0; k4 < 48; ++k4) {
            float4 gv = ((float4*)g)[k4];        // broadcast, conflict-free
            int kb = k4 * 4;
            unsigned int wp0 = Wl[(kb + 0) * 64 + lane];
            unsigned int wp1 = Wl[(kb + 1) * 64 + lane];
            unsigned int wp2 = Wl[(kb + 2) * 64 + lane];
            unsigned int wp3 = Wl[(kb + 3) * 64 + lane];
            acc0 += gv.x * bf_to_f((unsigned short)(wp0 & 0xffff));
            acc1 += gv.x * bf_to_f((unsigned short)(wp0 >> 16));
            acc0 += gv.y * bf_to_f((unsigned short)(wp1 & 0xffff));
            acc1 += gv.y * bf_to_f((unsigned short)(wp1 >> 16));
            acc0 += gv.z * bf_to_f((unsigned short)(wp2 & 0xffff));
            acc1 += gv.z * bf_to_f((unsigned short)(wp2 >> 16));
            acc0 += gv.w * bf_to_f((unsigned short)(wp3 & 0xffff));
            acc1 += gv.w * bf_to_f((unsigned short)(wp3 >> 16));
        }
        float2 e2 = ((const float2*)ent)[(size_t)n * 64 + lane];
        float x0 = acc0 + e2.x, x1 = acc1 + e2.y;
        float2 o;
        o.x = x0 > 0.f ? x0 : expm1f(x0);
        o.y = x1 > 0.f ? x1 : expm1f(x1);
        ((float2*)out)[(size_t)n * 64 + lane] = o;
    }
}

extern "C" void kernel_launch(void* const* d_in, const int* in_sizes, int n_in,
                              void* d_out, int out_size, void* d_ws, size_t ws_size,
                              hipStream_t stream) {
    const int*   tri  = (const int*)d_in[0];
    const float* ent  = (const float*)d_in[1];
    const float* attf = (const float*)d_in[2];
    const float* valf = (const float*)d_in[3];
    const float* aw   = (const float*)d_in[4];
    const float* ab   = (const float*)d_in[5];
    const float* W    = (const float*)d_in[6];
    float* out = (float*)d_out;

    char* ws = (char*)d_ws;
    size_t off = 0;
    int*   hist    = (int*)(ws + off);   off += NPAD * 4;
    int*   cursor  = (int*)(ws + off);   off += NPAD * 4;
    float* row_sum = (float*)(ws + off); off += NPAD * 4;
    size_t zero_len = off;
    int*   offs    = (int*)(ws + off);   off += NPAD * 4;
    int*   bsums   = (int*)(ws + off);   off += 512;
    float* s_ent   = (float*)(ws + off); off += NPAD * 4;
    float* s_att   = (float*)(ws + off); off += NPAD * 4;
    int*   sa      = (int*)(ws + off);   off += (size_t)N_EDGES * 4;
    int*   sv      = (int*)(ws + off);   off += (size_t)N_EDGES * 4;
    float* ssc     = (float*)(ws + off); off += (size_t)N_EDGES * 4;

    hipMemsetAsync(ws, 0, zero_len, stream);

    k_node_scores<<<N_NODES / 4, 256, 0, stream>>>(ent, attf, aw, s_ent, s_att);
    k_hist<<<(N_EDGES + 255) / 256, 256, 0, stream>>>(tri, hist);
    k_scan1<<<NT, 1024, 0, stream>>>(hist, offs, bsums);
    k_scan2<<<1, 64, 0, stream>>>(bsums);
    k_scan3<<<NPAD / 256, 256, 0, stream>>>(offs, bsums);
    k_edge_bucket<<<(N_EDGES + 255) / 256, 256, 0, stream>>>(tri, s_ent, s_att, ab, offs, cursor,
                                                             row_sum, sa, sv, ssc);
    k_agg<<<N_NODES / NPB, 256, 0, stream>>>(offs, row_sum, sa, sv, ssc,
                                             attf, valf, W, ent, out);
}

// Round 5
// 495.504 us; speedup vs baseline: 2.6457x; 1.4025x over previous
//
#include <hip/hip_runtime.h>
#include <hip/hip_bf16.h>

#define N_NODES 100000
#define N_EDGES 1000000
#define NPAD    100352          // nodes padded to 98*1024 for the scan
#define NT      98              // scan tiles of 1024
#define MPAD    100096          // GEMM M padded to 64-node blocks (1564*64)

typedef __attribute__((ext_vector_type(8))) short short8;
typedef __attribute__((ext_vector_type(4))) float float4_t;

__device__ __forceinline__ unsigned short f_to_bf(float f) {
    union { float f; unsigned int i; } c; c.f = f;
    unsigned int x = c.i;
    unsigned int r = x + 0x7fffu + ((x >> 16) & 1u);   // RTNE
    return (unsigned short)(r >> 16);
}
__device__ __forceinline__ int clampi(int x) {
    return x < 0 ? 0 : (x >= N_NODES ? N_NODES - 1 : x);
}

// K1: per-node score dots (f32). One wave per node.
__global__ __launch_bounds__(256)
void k_node_scores(const float* __restrict__ ent,
                   const float* __restrict__ attf,
                   const float* __restrict__ aw,
                   float* __restrict__ s_ent, float* __restrict__ s_att) {
    int node = (int)((blockIdx.x * blockDim.x + threadIdx.x) >> 6);
    int lane = threadIdx.x & 63;
    if (node >= N_NODES) return;
    const float2* aw2 = (const float2*)aw;
    float2 we = aw2[lane];
    float2 wa = aw2[64 + lane];
    float2 e2 = ((const float2*)ent)[(size_t)node * 64 + lane];
    float2 a2 = ((const float2*)attf)[(size_t)node * 64 + lane];
    float se = e2.x * we.x + e2.y * we.y;
    float sa = a2.x * wa.x + a2.y * wa.y;
#pragma unroll
    for (int off = 32; off >= 1; off >>= 1) {
        se += __shfl_xor(se, off, 64);
        sa += __shfl_xor(sa, off, 64);
    }
    if (lane == 0) { s_ent[node] = se; s_att[node] = sa; }
}

// K2: per-edge score + row_sum + hist (fused).
__global__ __launch_bounds__(256)
void k_edge_score(const int* __restrict__ tri,
                  const float* __restrict__ s_ent, const float* __restrict__ s_att,
                  const float* __restrict__ abp,
                  float* __restrict__ ssc_e, float* __restrict__ row_sum,
                  int* __restrict__ hist) {
    int e = (int)(blockIdx.x * blockDim.x + threadIdx.x);
    if (e >= N_EDGES) return;
    int h = clampi(tri[3 * e]);
    int a = clampi(tri[3 * e + 1]);
    float s = s_ent[h] + s_att[a] + abp[0];
    s = s > 0.f ? s : 0.2f * s;          // leaky_relu(0.2)
    float sc = __expf(s);
    ssc_e[e] = sc;
    atomicAdd(&row_sum[h], sc);
    atomicAdd(&hist[h], 1);
}

// K3a: per-tile exclusive scan + tile sums.
__global__ __launch_bounds__(1024)
void k_scan1(const int* __restrict__ hist, int* __restrict__ offs, int* __restrict__ bsums) {
    __shared__ int sd[1024];
    int t = threadIdx.x;
    int i = (int)blockIdx.x * 1024 + t;
    int x = hist[i];
    sd[t] = x;
    __syncthreads();
    for (int d = 1; d < 1024; d <<= 1) {
        int v = (t >= d) ? sd[t - d] : 0;
        __syncthreads();
        sd[t] += v;
        __syncthreads();
    }
    offs[i] = sd[t] - x;                 // exclusive
    if (t == 1023) bsums[blockIdx.x] = sd[t];
}

__global__ void k_scan2(int* __restrict__ bsums) {
    if (threadIdx.x == 0 && blockIdx.x == 0) {
        int acc = 0;
        for (int i = 0; i < NT; ++i) { int v = bsums[i]; bsums[i] = acc; acc += v; }
    }
}

__global__ __launch_bounds__(256)
void k_scan3(int* __restrict__ offs, const int* __restrict__ bsums) {
    int i = (int)(blockIdx.x * blockDim.x + threadIdx.x);
    if (i >= NPAD) return;
    offs[i] += bsums[i >> 10];
}

// K4: bucket placement. p = sc/row_sum pre-divided; one 16B AoS write per edge.
__global__ __launch_bounds__(256)
void k_bucket(const int* __restrict__ tri, const float* __restrict__ ssc_e,
              const float* __restrict__ row_sum,
              const int* __restrict__ offs, int* __restrict__ cursor,
              int4* __restrict__ edges) {
    int e = (int)(blockIdx.x * blockDim.x + threadIdx.x);
    if (e >= N_EDGES) return;
    int h = clampi(tri[3 * e]);
    int a = clampi(tri[3 * e + 1]);
    int v = clampi(tri[3 * e + 2]);
    float rs = row_sum[h];
    float p = ssc_e[e] * (rs > 0.f ? 1.f / rs : 0.f);
    int pos = offs[h] + atomicAdd(&cursor[h], 1);
    int4 ed; ed.x = a; ed.y = v; ed.z = __float_as_int(p); ed.w = 0;
    edges[pos] = ed;
}

// K5: wave-per-node gather -> G[node][192] bf16. NO LDS -> full occupancy.
__global__ __launch_bounds__(256)
void k_gather(const int* __restrict__ offs, const int4* __restrict__ edges,
              const float* __restrict__ attf, const float* __restrict__ valf,
              unsigned short* __restrict__ G) {
    int node = (int)blockIdx.x * 4 + (threadIdx.x >> 6);
    int lane = threadIdx.x & 63;
    if (node >= N_NODES) return;
    int beg = offs[node], end = offs[node + 1];
    float a0 = 0.f, a1 = 0.f, v0 = 0.f;
    for (int ib = beg; ib < end; ib += 64) {
        int lim = end - ib;
        int li = lane < lim ? lane : lim - 1;
        int4 ed = edges[ib + li];            // coalesced 16B batch load
        int cnt = lim < 64 ? lim : 64;
        for (int i = 0; i < cnt; ++i) {
            int a = __shfl(ed.x, i, 64);
            int v = __shfl(ed.y, i, 64);
            float p = __int_as_float(__shfl(ed.z, i, 64));
            float2 f = ((const float2*)attf)[(size_t)a * 64 + lane];
            float fv = valf[(size_t)v * 64 + lane];
            a0 += p * f.x; a1 += p * f.y; v0 += p * fv;
        }
    }
    ((unsigned int*)G)[(size_t)node * 96 + lane] =
        ((unsigned int)f_to_bf(a1) << 16) | (unsigned int)f_to_bf(a0);
    G[(size_t)node * 192 + 128 + lane] = f_to_bf(v0);
}

// K6a: transpose W -> Wt[col][k] bf16 (128 x 192).
__global__ __launch_bounds__(256)
void k_prepW(const float* __restrict__ W, unsigned short* __restrict__ Wt) {
    int i = (int)(blockIdx.x * blockDim.x + threadIdx.x);
    if (i >= 192 * 128) return;
    int c = i / 192, k = i - c * 192;
    Wt[i] = f_to_bf(W[k * 128 + c]);
}

// K6b: MFMA GEMM: out[m][c] = elu( G(M x 192) @ W(192 x 128) + ent ).
// Wave handles 16 nodes x 128 cols; 6 K-steps of 32.
// A layout: m=lane&15, k=quad*8+j. B (via Wt): n=lane&15, k=quad*8+j.
// C/D: col=lane&15, row=quad*4+reg.
__global__ __launch_bounds__(256)
void k_gemm(const unsigned short* __restrict__ G, const unsigned short* __restrict__ Wt,
            const float* __restrict__ ent, float* __restrict__ out) {
    int w = threadIdx.x >> 6, lane = threadIdx.x & 63;
    int quad = lane >> 4, mn = lane & 15;
    int nbase = (int)blockIdx.x * 64 + w * 16;
    float4_t acc[8];
#pragma unroll
    for (int i = 0; i < 8; ++i) acc[i] = (float4_t){0.f, 0.f, 0.f, 0.f};
    const short8* Gp = (const short8*)(G + (size_t)(nbase + mn) * 192 + quad * 8);
    const short8* Wp = (const short8*)(Wt + (size_t)mn * 192 + quad * 8);
#pragma unroll
    for (int kt = 0; kt < 6; ++kt) {
        short8 afr = Gp[kt * 4];
#pragma unroll
        for (int ct = 0; ct < 8; ++ct) {
            short8 bfr = Wp[kt * 4 + ct * 384];     // +16 cols = 16*192/8 short8
            acc[ct] = __builtin_amdgcn_mfma_f32_16x16x32_bf16(afr, bfr, acc[ct], 0, 0, 0);
        }
    }
#pragma unroll
    for (int ct = 0; ct < 8; ++ct) {
        int col = ct * 16 + mn;
#pragma unroll
        for (int r = 0; r < 4; ++r) {
            int node = nbase + quad * 4 + r;
            if (node < N_NODES) {
                float x = acc[ct][r] + ent[(size_t)node * 128 + col];
                out[(size_t)node * 128 + col] = x > 0.f ? x : expm1f(x);
            }
        }
    }
}

extern "C" void kernel_launch(void* const* d_in, const int* in_sizes, int n_in,
                              void* d_out, int out_size, void* d_ws, size_t ws_size,
                              hipStream_t stream) {
    const int*   tri  = (const int*)d_in[0];
    const float* ent  = (const float*)d_in[1];
    const float* attf = (const float*)d_in[2];
    const float* valf = (const float*)d_in[3];
    const float* aw   = (const float*)d_in[4];
    const float* ab   = (const float*)d_in[5];
    const float* W    = (const float*)d_in[6];
    float* out = (float*)d_out;

    char* ws = (char*)d_ws;
    size_t off = 0;
    int*   hist    = (int*)(ws + off);   off += NPAD * 4;
    int*   cursor  = (int*)(ws + off);   off += NPAD * 4;
    float* row_sum = (float*)(ws + off); off += NPAD * 4;
    size_t zero_len = off;
    int*   offs    = (int*)(ws + off);   off += NPAD * 4;
    int*   bsums   = (int*)(ws + off);   off += 512;
    float* s_ent   = (float*)(ws + off); off += NPAD * 4;
    float* s_att   = (float*)(ws + off); off += NPAD * 4;
    float* ssc_e   = (float*)(ws + off); off += (size_t)N_EDGES * 4;
    int4*  edges   = (int4*)(ws + off);  off += (size_t)N_EDGES * 16;
    unsigned short* G  = (unsigned short*)(ws + off); off += (size_t)MPAD * 192 * 2;
    unsigned short* Wt = (unsigned short*)(ws + off); off += 192 * 128 * 2;
    // total ~61 MB

    hipMemsetAsync(ws, 0, zero_len, stream);

    k_node_scores<<<N_NODES / 4, 256, 0, stream>>>(ent, attf, aw, s_ent, s_att);
    k_prepW<<<(192 * 128 + 255) / 256, 256, 0, stream>>>(W, Wt);
    k_edge_score<<<(N_EDGES + 255) / 256, 256, 0, stream>>>(tri, s_ent, s_att, ab,
                                                            ssc_e, row_sum, hist);
    k_scan1<<<NT, 1024, 0, stream>>>(hist, offs, bsums);
    k_scan2<<<1, 64, 0, stream>>>(bsums);
    k_scan3<<<NPAD / 256, 256, 0, stream>>>(offs, bsums);
    k_bucket<<<(N_EDGES + 255) / 256, 256, 0, stream>>>(tri, ssc_e, row_sum, offs, cursor, edges);
    k_gather<<<(N_NODES + 3) / 4, 256, 0, stream>>>(offs, edges, attf, valf, G);
    k_gemm<<<(MPAD) / 64, 256, 0, stream>>>(G, Wt, ent, out);
}